// Round 16
// baseline (6265.868 us; speedup 1.0000x reference)
//
#include <hip/hip_runtime.h>

// ---------------------------------------------------------------------------
// MPNODE_STL10 forward, round 25: r23 base + bf16-only z (transient).
//  - r24 (depth-2 prefetch) regressed -> reverted; r23 structure restored.
//  - z (conv1 out -> conv2 in, per-substep transient, non-accumulating) is
//    now plain bf16: conv1 stores u16; conv2 stages single-plane LDS
//    (25.9KB), normalizes the bf16 value, and runs 2 MFMAs/kp (B lo plane
//    gone; A keeps hi+lo). State t / y stay split-u32 / fp32 -> RK chain
//    numerics preserved. Stats unchanged (full-precision epilogue regs).
//  - Precision budget: absmax 4.9e-4, threshold 9.0e-3 (18x headroom);
//    expected rise to ~2-5e-3. Fallback: revert to r23.
//  - Everything else verbatim r23 (verified 5289.6us best): goff hoist,
//    bulk A[9] prefetch, parallel stats reduce, per-WG partials, shapes.
// ---------------------------------------------------------------------------

typedef __attribute__((ext_vector_type(8)))  short  s16x8;
typedef __attribute__((ext_vector_type(16))) float  f32x16;

__device__ __forceinline__ unsigned short bf16_rtne(float f) {
    unsigned u = __builtin_bit_cast(unsigned, f);
    unsigned r = u + 0x7FFFu + ((u >> 16) & 1u);
    return (unsigned short)(r >> 16);
}
__device__ __forceinline__ void split2(float v, unsigned& h, unsigned& l) {
    unsigned u = __builtin_bit_cast(unsigned, v);
    h = (u + 0x7fffu + ((u >> 16) & 1u)) >> 16;
    float r = v - __builtin_bit_cast(float, h << 16);
    unsigned ur = __builtin_bit_cast(unsigned, r);
    l = (ur + 0x7fffu + ((ur >> 16) & 1u)) >> 16;
}
__device__ __forceinline__ unsigned packsplit(float v) {
    unsigned h, l; split2(v, h, l); return h | (l << 16);
}

// ---------------- weight pack (verified rounds 4-24) -----------------------
// Per dir (0=conv, 1=transposed+flipped), per bank(4):
//   [icc(C/16)][mt(C/32)][kp(9)][pl(2: hi,lo)][lane(64)][j(8)]
__global__ __launch_bounds__(256) void pack_weights(
    const float* __restrict__ Wb, unsigned short* __restrict__ out, int C)
{
    const int dir = blockIdx.y;
    const int MT = C >> 5, ICC = C >> 4;
    const size_t TOT = (size_t)36 * C * C;
    size_t t = (size_t)blockIdx.x * 256 + threadIdx.x;
    if (t >= TOT) return;
    int j = t & 7;
    int l = (t >> 3) & 63;
    size_t r = t >> 9;
    int kp  = r % 9;  r /= 9;
    int mt  = r % MT; r /= MT;
    int icc = r % ICC; r /= ICC;
    int bank = (int)r;
    int oc = mt * 32 + (l & 31);
    int ic = icc * 16 + (l >> 5) * 8 + j;
    int kh = kp / 3, kw = kp % 3;
    float v;
    if (dir == 0)
        v = Wb[(((size_t)(bank * C + oc) * C + ic) * 3 + kh) * 3 + kw];
    else
        v = Wb[(((size_t)(bank * C + ic) * C + oc) * 3 + (2 - kh)) * 3 + (2 - kw)];
    unsigned short h = bf16_rtne(v);
    float hf = __builtin_bit_cast(float, (unsigned)h << 16);
    unsigned short lo = bf16_rtne(v - hf);
    size_t idx = ((((size_t)bank * ICC + icc) * MT + mt) * 9 + kp) * 1024 + l * 8 + j;
    unsigned short* base = out + (size_t)dir * 72 * C * C;
    base[idx] = h;
    base[idx + 512] = lo;
}

// ---------------- MFMA conv kernel -----------------------------------------
// MODE 0: conv1, fp32 input (k1 stages from y); z out as bf16 u16
// MODE 1: conv1, split-u32 input (k2-k4 stage from t); z out as bf16 u16
// MODE 2: conv2, bf16-u16 input (z) + instnorm; single-plane B; RK4 epilogue
// Stats: conv1 stores per-WG partials part[(n*MT+mt)*tilesT+tile][64]
//        ([0..31]=sum per oc, [32..63]=sumsq); conv2 reduces over tilesT.
template<int NW, int MODE>
__global__ __launch_bounds__(NW * 64) void conv_mfma4(
    const void* __restrict__ in,
    const unsigned short* __restrict__ pA,
    const float* __restrict__ bias,
    const float* __restrict__ partI,         // conv2: read partials
    float* __restrict__ partO,               // conv1: write partials
    const float* __restrict__ ybase, float* __restrict__ accb,
    float* __restrict__ ydstF, void* __restrict__ ydstS,
    int C, int H, int W, int tilesX, int tilesT, float inv_hw,
    int mode, float acoef, float dt6)
{
    constexpr bool CONV2 = (MODE == 2);
    constexpr int TPX = 16, TPY = 2 * NW;
    constexpr int HX = TPX + 2, HY = TPY + 2;
    constexpr int NROW = HX * HY;
    constexpr int RS = 20;               // row stride (shorts), 40B
    constexpr int PL = NROW * RS;
    constexpr int NPLN = CONV2 ? 1 : 2;  // conv2: hi plane only
    constexpr int BUFS = NPLN * PL;
    constexpr int NTHR = NW * 64;
    constexpr int NELEM = NROW * 16;
    constexpr int NIT = (NELEM + NTHR - 1) / NTHR;
    __shared__ __align__(16) unsigned short sB[2 * BUFS];
    __shared__ float sTab[CONV2 ? 512 : 4];

    const int tid = threadIdx.x;
    const int w = tid >> 6, lane = tid & 63;
    const int n = blockIdx.x;            // fastest dim -> image n on XCD n
    const int tile = blockIdx.y;
    const int mt = blockIdx.z;
    const int tileX = tile % tilesX, tileY = tile / tilesX;
    const int px0 = tileX * TPX, py0 = tileY * TPY;
    const int ocb = mt * 32;
    const int HW = H * W;
    const int ICC = C >> 4, MT = C >> 5;
    const int col = lane & 31, half = lane >> 5;
    const int xl = col & 15, yr = col >> 4;
    const int wy0 = 2 * w;
    const int ncbase = n * C;

    // ---- per-item staging geometry, invariant across icc chunks ----
    int goff[NIT];
#pragma unroll
    for (int i = 0; i < NIT; i++) {
        int e = tid + i * NTHR;
        int o = (int)0x80000000;
        if (e < NELEM) {
            int ic = e / NROW; int r = e - ic * NROW;
            int yy = r / HX, xx = r - yy * HX;
            int gy = py0 + yy - 1, gx = px0 + xx - 1;
            if (gy >= 0 && gy < H && gx >= 0 && gx < W)
                o = (ncbase + ic) * HW + gy * W + gx;
        }
        goff[i] = o;
    }

    float stg[NIT];
    // MODE 0: fp32 load; MODE 1: split-u32 bit pattern; MODE 2: bf16 decode
    auto stageLoad = [&](int icc) {
        const int cofs = icc * 16 * HW;
#pragma unroll
        for (int i = 0; i < NIT; i++) {
            float v = 0.f;
            int o = goff[i];
            if (o >= 0) {
                if (MODE == 0)
                    v = ((const float*)in)[o + cofs];
                else if (MODE == 1)
                    v = __builtin_bit_cast(float, ((const unsigned*)in)[o + cofs]);
                else {
                    unsigned short uu = ((const unsigned short*)in)[o + cofs];
                    v = __builtin_bit_cast(float, (unsigned)uu << 16);
                }
            }
            stg[i] = v;
        }
    };
    // MODE 2 normalizes here (needs sTab, available after the stats barrier)
    auto stageWrite = [&](int b, int c0) {
#pragma unroll
        for (int i = 0; i < NIT; i++) {
            int e = tid + i * NTHR;
            if (e < NELEM) {
                int ic = e / NROW; int r = e - ic * NROW;
                int off = b * BUFS + r * RS + ic;
                if (MODE == 1) {
                    unsigned u = __builtin_bit_cast(unsigned, stg[i]);
                    sB[off] = (unsigned short)(u & 0xffffu);
                    sB[off + PL] = (unsigned short)(u >> 16);
                } else if (MODE == 2) {
                    float v = 0.f;
                    if (goff[i] >= 0) {
                        int c = c0 + ic;
                        v = (stg[i] - sTab[2 * c]) * sTab[2 * c + 1];
                    }
                    sB[off] = bf16_rtne(v);
                } else {
                    unsigned h, l;
                    split2(stg[i], h, l);
                    sB[off] = (unsigned short)h;
                    sB[off + PL] = (unsigned short)l;
                }
            }
        }
    };
    auto loadB = [&](int b, int kp, s16x8& oh, s16x8& ol) {
        int kh = kp / 3, kw = kp - kh * 3;
        int px = (wy0 + yr + kh) * HX + (xl + kw);
        int off = b * BUFS + px * RS + half * 8;
        oh = *(const s16x8*)&sB[off];
        if (!CONV2) ol = *(const s16x8*)&sB[off + PL];
    };

    f32x16 accA{}, accB{}, accC{};

    // issue chunk-0 loads first: latency hides under the stats reduce
    stageLoad(0);

    // conv2: per-channel mu/rstd from conv1's per-tile partials.
    if (CONV2) {
        float* sRed = (float*)sB;        // scratch; free until stageWrite(0)
        const int g = NTHR / C;          // slices per channel (>=1)
        {
            int c0 = tid % C, sl = tid / C;
            int mtc = c0 >> 5, occ = c0 & 31;
            int t0 = (tilesT * sl) / g, t1 = (tilesT * (sl + 1)) / g;
            const float* pb = partI + ((size_t)(n * MT + mtc) * tilesT) * 64 + occ;
            float S = 0.f, Q = 0.f;
            for (int tt = t0; tt < t1; ++tt) {
                S += pb[(size_t)tt * 64];
                Q += pb[(size_t)tt * 64 + 32];
            }
            sRed[tid] = S;
            sRed[NTHR + tid] = Q;
        }
        __syncthreads();
        if (tid < C) {
            float s = 0.f, q = 0.f;
            for (int k = 0; k < g; ++k) {
                s += sRed[k * C + tid];
                q += sRed[NTHR + k * C + tid];
            }
            float m = s * inv_hw;
            sTab[2 * tid] = m;
            sTab[2 * tid + 1] = rsqrtf(fmaf(-m, m, q * inv_hw) + 1e-5f);
        }
        __syncthreads();
    }

    stageWrite(0, 0);
    __syncthreads();

    for (int icc = 0; icc < ICC; ++icc) {
        // ---- bulk A loads: whole chunk's 9 kp hi+lo into regs ----
        s16x8 aH[9], aL[9];
        {
            const unsigned short* ab =
                pA + ((size_t)(icc * MT + mt)) * 9216 + lane * 8;
#pragma unroll
            for (int kp = 0; kp < 9; ++kp) {
                aH[kp] = *(const s16x8*)(ab + kp * 1024);
                aL[kp] = *(const s16x8*)(ab + kp * 1024 + 512);
            }
        }
        const int b = icc & 1;
        if (icc + 1 < ICC) stageLoad(icc + 1);   // stays outstanding over MFMAs

        s16x8 bh, bl;
        loadB(b, 0, bh, bl);
#pragma unroll
        for (int kp = 0; kp < 9; ++kp) {
            s16x8 bhn, bln;
            if (kp < 8) loadB(b, kp + 1, bhn, bln);
            accA = __builtin_amdgcn_mfma_f32_32x32x16_bf16(aH[kp], bh, accA, 0, 0, 0);
            accB = __builtin_amdgcn_mfma_f32_32x32x16_bf16(aL[kp], bh, accB, 0, 0, 0);
            if (!CONV2)
                accC = __builtin_amdgcn_mfma_f32_32x32x16_bf16(aH[kp], bl, accC, 0, 0, 0);
            if (kp < 8) { bh = bhn; bl = bln; }
        }
        if (icc + 1 < ICC) {
            stageWrite(b ^ 1, (icc + 1) * 16);
            __syncthreads();
        }
    }

    // ---- epilogue: C/D layout col=lane&31, row=(r&3)+8*(r>>2)+4*half ----
    const int gx = px0 + xl;
    const int gy = py0 + wy0 + yr;
    const bool valid = (gx < W);
    const size_t base0 = (size_t)(ncbase + ocb) * HW + (size_t)gy * W + gx;
    float* sred = (float*)sB;   // last chunk used buffer 1 (ICC even); buf 0 free
#pragma unroll
    for (int r = 0; r < 16; r++) {
        int row = (r & 3) + 8 * (r >> 2) + 4 * half;
        int oc = ocb + row;
        size_t idx = base0 + (size_t)(row * HW);
        float v = accA[r] + accB[r];
        if (!CONV2) v += accC[r];
        if (!CONV2) {
            v += bias[oc];
            v = fmaxf(v, 0.f);
            if (valid) ((unsigned short*)ydstS)[idx] = bf16_rtne(v);  // z, bf16
            float s = valid ? v : 0.f;
            float sq = s * s;
#pragma unroll
            for (int m = 1; m < 32; m <<= 1) {
                s  += __shfl_xor(s, m, 64);
                sq += __shfl_xor(sq, m, 64);
            }
            if ((lane & 31) == 0) {
                int slot = ((w * 2 + half) * 16 + r) * 2;
                sred[slot] = s;
                sred[slot + 1] = sq;
            }
        } else if (valid) {
            float k = -v;
            if (mode == 0) {
                accb[idx] = k;
                ((unsigned*)ydstS)[idx] = packsplit(ybase[idx] + acoef * k);  // t
            } else if (mode == 3) {
                ydstF[idx] = ybase[idx] + dt6 * (accb[idx] + k);  // y, fp32
            } else {
                accb[idx] += 2.f * k;
                ((unsigned*)ydstS)[idx] = packsplit(ybase[idx] + acoef * k);  // t
            }
        }
    }
    if (!CONV2) {
        __syncthreads();
        if (tid < 32) {
            // row==tid mapping (verified): tid bits = (r&3)|h2<<2|(r>>2)<<3
            int h2 = (tid >> 2) & 1;
            int r  = (tid & 3) | ((tid >> 3) << 2);
            float s = 0.f, sq = 0.f;
#pragma unroll
            for (int wv = 0; wv < NW; wv++) {
                int slot = ((wv * 2 + h2) * 16 + r) * 2;
                s  += sred[slot];
                sq += sred[slot + 1];
            }
            float* po = partO + ((size_t)(n * MT + mt) * tilesT + tile) * 64;
            po[tid] = s;
            po[tid + 32] = sq;
        }
    }
}

// ---------------- fp32 stem conv (Cin=3, Cout=64, 2 px/thread) -------------
__global__ __launch_bounds__(256) void conv3x3_stem(
    const float* __restrict__ in, const float* __restrict__ w,
    const float* __restrict__ bias, float* __restrict__ out,
    int H, int W, int tilesX)
{
    __shared__ float sIn[3][18][34];
    __shared__ float sW[16][3][9];
    const int tid = threadIdx.x;
    const int tx = tid & 15, ty = tid >> 4;
    const int tileX = blockIdx.x % tilesX, tileY = blockIdx.x / tilesX;
    const int x0 = tileX * 32, y0 = tileY * 16;
    const int oc0 = blockIdx.y * 16;
    const int n = blockIdx.z;
    const int HW = H * W;

    for (int idx = tid; idx < 3 * 18 * 34; idx += 256) {
        int c = idx / (18 * 34); int r = idx % (18 * 34);
        int iy = r / 34, ix = r % 34;
        int gy = y0 + iy - 1, gx = x0 + ix - 1;
        float v = 0.f;
        if (gy >= 0 && gy < H && gx >= 0 && gx < W)
            v = in[(size_t)(n * 3 + c) * HW + gy * W + gx];
        sIn[c][iy][ix] = v;
    }
    for (int idx = tid; idx < 16 * 27; idx += 256) {
        int o = idx / 27, r = idx % 27;
        sW[o][r / 9][r % 9] = w[(size_t)(oc0 + o) * 27 + r];
    }
    __syncthreads();

    float a0[16], a1[16];
#pragma unroll
    for (int o = 0; o < 16; o++) { a0[o] = 0.f; a1[o] = 0.f; }
#pragma unroll
    for (int c = 0; c < 3; c++)
#pragma unroll
        for (int kh = 0; kh < 3; kh++)
#pragma unroll
            for (int kw = 0; kw < 3; kw++) {
                float v0 = sIn[c][ty + kh][tx + kw];
                float v1 = sIn[c][ty + kh][tx + 16 + kw];
#pragma unroll
                for (int o = 0; o < 16; o++) {
                    float wv = sW[o][c][kh * 3 + kw];
                    a0[o] = fmaf(v0, wv, a0[o]);
                    a1[o] = fmaf(v1, wv, a1[o]);
                }
            }

    const int gy = y0 + ty, gx = x0 + tx;
#pragma unroll
    for (int o = 0; o < 16; o++) {
        float bb = bias[oc0 + o];
        size_t base = (size_t)(n * 64 + oc0 + o) * HW + (size_t)gy * W + gx;
        out[base] = a0[o] + bb;
        out[base + 16] = a1[o] + bb;
    }
}

// ---------------- instance-norm stats (stem/conn/head only) ----------------
__global__ __launch_bounds__(256) void stats_kernel(
    const float* __restrict__ x, float* __restrict__ mu, float* __restrict__ rstd,
    int HW, float inv_hw)
{
    int nc = blockIdx.x;
    const float* p = x + (size_t)nc * HW;
    float s = 0.f, ss = 0.f;
    for (int i = threadIdx.x; i < HW; i += 256) {
        float v = p[i];
        s += v;
        ss = fmaf(v, v, ss);
    }
    for (int off = 32; off; off >>= 1) {
        s  += __shfl_down(s, off, 64);
        ss += __shfl_down(ss, off, 64);
    }
    __shared__ float aS[4], aSS[4];
    int wid = threadIdx.x >> 6, lane = threadIdx.x & 63;
    if (lane == 0) { aS[wid] = s; aSS[wid] = ss; }
    __syncthreads();
    if (threadIdx.x == 0) {
        s  = aS[0] + aS[1] + aS[2] + aS[3];
        ss = aSS[0] + aSS[1] + aSS[2] + aSS[3];
        float m = s * inv_hw;
        float var = fmaf(-m, m, ss * inv_hw);
        mu[nc] = m;
        rstd[nc] = rsqrtf(var + 1e-5f);
    }
}

__global__ __launch_bounds__(256) void norm_affine_relu_kernel(
    const float* __restrict__ in, float* __restrict__ out,
    const float* __restrict__ mu, const float* __restrict__ rstd,
    const float* __restrict__ g, const float* __restrict__ b,
    int C, int HW, size_t total)
{
    size_t i = (size_t)blockIdx.x * 256 + threadIdx.x;
    if (i >= total) return;
    size_t nc = i / HW;
    int c = (int)(nc % C);
    float v = (in[i] - mu[nc]) * rstd[nc] * g[c] + b[c];
    out[i] = fmaxf(v, 0.f);
}

// ---------------- fused norm+relu+avgpool2 (conn blocks) -------------------
__global__ __launch_bounds__(256) void norm_pool_kernel(
    const float* __restrict__ in, float* __restrict__ out,
    const float* __restrict__ mu, const float* __restrict__ rstd,
    const float* __restrict__ g, const float* __restrict__ b,
    int C, int Ho, int Wo, size_t total)
{
    size_t i = (size_t)blockIdx.x * 256 + threadIdx.x;
    if (i >= total) return;
    int wo = (int)(i % Wo);
    int ho = (int)((i / Wo) % Ho);
    size_t nc = i / ((size_t)Wo * Ho);
    int c = (int)(nc % C);
    const int Wi = 2 * Wo;
    const float* p = in + nc * (size_t)(4 * Ho * Wo) + (size_t)(2 * ho) * Wi + 2 * wo;
    float sc  = rstd[nc] * g[c];
    float off = fmaf(-mu[nc], sc, b[c]);
    float2 t0 = *(const float2*)p;
    float2 t1 = *(const float2*)(p + Wi);
    float s = fmaxf(fmaf(t0.x, sc, off), 0.f) + fmaxf(fmaf(t0.y, sc, off), 0.f)
            + fmaxf(fmaf(t1.x, sc, off), 0.f) + fmaxf(fmaf(t1.y, sc, off), 0.f);
    out[i] = 0.25f * s;
}

// ---------------- 1x1 conv: 4 px/thread via float4, ILP ic loop ------------
#define C1OCT 8
__global__ __launch_bounds__(256) void conv1x1_kernel(
    const float* __restrict__ in, const float* __restrict__ w,
    const float* __restrict__ bias, float* __restrict__ out,
    int Cin, int Cout, int HW)
{
    const int HW4 = HW >> 2;
    int p = blockIdx.x * 256 + threadIdx.x;
    if (p >= HW4) return;
    const int oc0 = blockIdx.y * C1OCT;
    const int n = blockIdx.z;
    const float4* ip = (const float4*)(in + (size_t)n * Cin * HW) + p;
    float acc[C1OCT][4];
#pragma unroll
    for (int o = 0; o < C1OCT; o++)
        acc[o][0] = acc[o][1] = acc[o][2] = acc[o][3] = 0.f;
#pragma unroll 4
    for (int ic = 0; ic < Cin; ic++) {
        float4 v = ip[(size_t)ic * HW4];
#pragma unroll
        for (int o = 0; o < C1OCT; o++) {
            float wv = w[(size_t)(oc0 + o) * Cin + ic];
            acc[o][0] = fmaf(v.x, wv, acc[o][0]);
            acc[o][1] = fmaf(v.y, wv, acc[o][1]);
            acc[o][2] = fmaf(v.z, wv, acc[o][2]);
            acc[o][3] = fmaf(v.w, wv, acc[o][3]);
        }
    }
    float4* op = (float4*)(out + ((size_t)n * Cout + oc0) * HW) + p;
#pragma unroll
    for (int o = 0; o < C1OCT; o++) {
        float bb = bias[oc0 + o];
        float4 r;
        r.x = acc[o][0] + bb; r.y = acc[o][1] + bb;
        r.z = acc[o][2] + bb; r.w = acc[o][3] + bb;
        op[(size_t)o * HW4] = r;
    }
}

__global__ __launch_bounds__(128) void head_kernel(
    const float* __restrict__ m, const float* __restrict__ hw,
    const float* __restrict__ hb, float* __restrict__ out, int C)
{
    int t = threadIdx.x;
    if (t < 80) {
        int n = t / 10, k = t % 10;
        float acc = hb[k];
        for (int c = 0; c < C; c++)
            acc = fmaf(m[n * C + c], hw[k * C + c], acc);
        out[t] = acc;
    }
}

// ---------------------------------------------------------------------------
// host orchestration
// ---------------------------------------------------------------------------
struct OdeCfg { int C, H, tilesX, tilesT; };
// stage0: NW=8 -> tile 16x16: 6x6 = 36 tiles
// stage1: NW=4 -> tile 16x8:  3x6 = 18 tiles
// stage2: NW=4 -> tile 16x8:  2x3 = 6 tiles (x-masked)
static const OdeCfg CFG[3] = {
    {64, 96, 6, 36},
    {128, 48, 3, 18},
    {256, 24, 2, 6},
};

static void launch_c1(int st, int inMode, const void* in, const unsigned short* pA,
                      const float* bias, float* part, void* z, hipStream_t s)
{
    const OdeCfg& c = CFG[st];
    dim3 g(8, c.tilesT, c.C / 32);   // n fastest -> image n on XCD n
    float ih = 1.f / (c.H * c.H);
    if (st == 0) {
        if (inMode == 0)
            conv_mfma4<8, 0><<<g, 512, 0, s>>>(in, pA, bias,
                nullptr, part, nullptr, nullptr, nullptr, z,
                c.C, c.H, c.H, c.tilesX, c.tilesT, ih, 0, 0.f, 0.f);
        else
            conv_mfma4<8, 1><<<g, 512, 0, s>>>(in, pA, bias,
                nullptr, part, nullptr, nullptr, nullptr, z,
                c.C, c.H, c.H, c.tilesX, c.tilesT, ih, 0, 0.f, 0.f);
    } else {
        if (inMode == 0)
            conv_mfma4<4, 0><<<g, 256, 0, s>>>(in, pA, bias,
                nullptr, part, nullptr, nullptr, nullptr, z,
                c.C, c.H, c.H, c.tilesX, c.tilesT, ih, 0, 0.f, 0.f);
        else
            conv_mfma4<4, 1><<<g, 256, 0, s>>>(in, pA, bias,
                nullptr, part, nullptr, nullptr, nullptr, z,
                c.C, c.H, c.H, c.tilesX, c.tilesT, ih, 0, 0.f, 0.f);
    }
}

static void launch_c2(int st, const void* z, const unsigned short* pA,
                      const float* part,
                      const float* ybase, float* accb,
                      float* ydstF, void* ydstS,
                      int mode, float acoef, hipStream_t s)
{
    const OdeCfg& c = CFG[st];
    dim3 g(8, c.tilesT, c.C / 32);
    float ih = 1.f / (c.H * c.H);
    const float dt6 = 0.25f / 6.f;
    if (st == 0)
        conv_mfma4<8, 2><<<g, 512, 0, s>>>(z, pA, nullptr,
            part, nullptr, ybase, accb, ydstF, ydstS,
            c.C, c.H, c.H, c.tilesX, c.tilesT, ih, mode, acoef, dt6);
    else
        conv_mfma4<4, 2><<<g, 256, 0, s>>>(z, pA, nullptr,
            part, nullptr, ybase, accb, ydstF, ydstS,
            c.C, c.H, c.H, c.tilesX, c.tilesT, ih, mode, acoef, dt6);
}

static void ode_block_mfma(int st, float* y, unsigned* t, void* z, float* a,
                           float* part, unsigned short* pack,
                           const float* bbank, hipStream_t s)
{
    const OdeCfg& c = CFG[st];
    const int C = c.C;
    const size_t BANKW = (size_t)18 * C * C;   // one bank, one dir
    const size_t DIRW  = (size_t)72 * C * C;   // 4 banks
    const float dt = 0.25f;
    for (int i = 0; i < 4; i++) {
        int j = (i + 1 > 3) ? 3 : i + 1;
        const unsigned short* p1  = pack + i * BANKW;         // dir0, bank i
        const unsigned short* p1t = pack + DIRW + i * BANKW;  // dir1, bank i
        const unsigned short* p4  = pack + j * BANKW;
        const unsigned short* p4t = pack + DIRW + j * BANKW;
        const float* b1 = bbank + (size_t)i * C;
        const float* b4 = bbank + (size_t)j * C;

        // k1 (from fp32 y)
        launch_c1(st, 0, y, p1, b1, part, z, s);
        launch_c2(st, z, p1t, part, y, a, nullptr, t, 0, 0.5f * dt, s);
        // k2 (from split t)
        launch_c1(st, 1, t, p1, b1, part, z, s);
        launch_c2(st, z, p1t, part, y, a, nullptr, t, 1, 0.5f * dt, s);
        // k3
        launch_c1(st, 1, t, p1, b1, part, z, s);
        launch_c2(st, z, p1t, part, y, a, nullptr, t, 1, dt, s);
        // k4 + update (y out, fp32)
        launch_c1(st, 1, t, p4, b4, part, z, s);
        launch_c2(st, z, p4t, part, y, a, y, t, 3, 0.f, s);
    }
}

extern "C" void kernel_launch(void* const* d_in, const int* in_sizes, int n_in,
                              void* d_out, int out_size, void* d_ws, size_t ws_size,
                              hipStream_t stream)
{
    const float* x       = (const float*)d_in[0];
    const float* stem_w  = (const float*)d_in[1];
    const float* stem_b  = (const float*)d_in[2];
    const float* norm1_g = (const float*)d_in[3];
    const float* norm1_b = (const float*)d_in[4];
    const float* ode1_W  = (const float*)d_in[5];
    const float* ode1_b  = (const float*)d_in[6];
    const float* conn1_w = (const float*)d_in[7];
    const float* conn1_b = (const float*)d_in[8];
    const float* norm3_g = (const float*)d_in[9];
    const float* norm3_b = (const float*)d_in[10];
    const float* ode2_W  = (const float*)d_in[11];
    const float* ode2_b  = (const float*)d_in[12];
    const float* conn2_w = (const float*)d_in[13];
    const float* conn2_b = (const float*)d_in[14];
    const float* norm4_g = (const float*)d_in[15];
    const float* norm4_b = (const float*)d_in[16];
    const float* ode3_W  = (const float*)d_in[17];
    const float* ode3_b  = (const float*)d_in[18];
    const float* head_w  = (const float*)d_in[19];
    const float* head_b  = (const float*)d_in[20];
    float* out = (float*)d_out;

    float* ws = (float*)d_ws;
    const size_t BUF = 4718592; // 8*64*96*96 elements
    float*    y  = ws;
    unsigned* t  = (unsigned*)(ws + BUF);     // split-bf16 state t / conn scratch
    void*     z  = (void*)(ws + 2 * BUF);     // bf16-u16 activations z
    float*    a  = ws + 3 * BUF;              // fp32 RK4 accumulator
    float*    mu = ws + 4 * BUF;              // 2048
    float*    rs = mu + 2048;                 // 2048
    float*    part = ws + 4 * BUF + 4096;     // per-WG stats partials (36864)
    unsigned short* pack = (unsigned short*)(ws + 4 * BUF + 4096 + 36864);
    float* tf = (float*)t;                    // conn scratch reuse (fp32)

    // ---- stem: conv3x3(3->64)+b -> IN(affine) -> relu ----
    {
        int H = 96;
        dim3 grid(3 * 6, 4, 8);              // 32x16 tiles, 16-oc blocks
        conv3x3_stem<<<grid, 256, 0, stream>>>(x, stem_w, stem_b, (float*)z,
                                               H, H, 3);
        stats_kernel<<<8 * 64, 256, 0, stream>>>((float*)z, mu, rs, H * H, 1.f / (H * H));
        size_t total = (size_t)8 * 64 * H * H;
        norm_affine_relu_kernel<<<(total + 255) / 256, 256, 0, stream>>>(
            (float*)z, y, mu, rs, norm1_g, norm1_b, 64, H * H, total);
    }

    // ---- ode1 ----
    {
        size_t TOT = (size_t)36 * 64 * 64;
        pack_weights<<<dim3((TOT + 255) / 256, 2), 256, 0, stream>>>(ode1_W, pack, 64);
        ode_block_mfma(0, y, t, z, a, part, pack, ode1_b, stream);
    }

    // ---- conn1: 1x1(64->128) -> IN+relu -> pool (fused) ----
    {
        int H = 96, HW = H * H, Cin = 64, Cout = 128;
        dim3 grid((HW / 4 + 255) / 256, Cout / C1OCT, 8);
        conv1x1_kernel<<<grid, 256, 0, stream>>>(y, conn1_w, conn1_b, tf, Cin, Cout, HW);
        stats_kernel<<<8 * Cout, 256, 0, stream>>>(tf, mu, rs, HW, 1.f / HW);
        size_t ptotal = (size_t)8 * Cout * 48 * 48;
        norm_pool_kernel<<<(ptotal + 255) / 256, 256, 0, stream>>>(
            tf, y, mu, rs, norm3_g, norm3_b, Cout, 48, 48, ptotal);
    }

    // ---- ode2 ----
    {
        size_t TOT = (size_t)36 * 128 * 128;
        pack_weights<<<dim3((TOT + 255) / 256, 2), 256, 0, stream>>>(ode2_W, pack, 128);
        ode_block_mfma(1, y, t, z, a, part, pack, ode2_b, stream);
    }

    // ---- conn2: 1x1(128->256) -> IN+relu -> pool (fused) ----
    {
        int H = 48, HW = H * H, Cin = 128, Cout = 256;
        dim3 grid((HW / 4 + 255) / 256, Cout / C1OCT, 8);
        conv1x1_kernel<<<grid, 256, 0, stream>>>(y, conn2_w, conn2_b, tf, Cin, Cout, HW);
        stats_kernel<<<8 * Cout, 256, 0, stream>>>(tf, mu, rs, HW, 1.f / HW);
        size_t ptotal = (size_t)8 * Cout * 24 * 24;
        norm_pool_kernel<<<(ptotal + 255) / 256, 256, 0, stream>>>(
            tf, y, mu, rs, norm4_g, norm4_b, Cout, 24, 24, ptotal);
    }

    // ---- ode3 ----
    {
        size_t TOT = (size_t)36 * 256 * 256;
        pack_weights<<<dim3((TOT + 255) / 256, 2), 256, 0, stream>>>(ode3_W, pack, 256);
        ode_block_mfma(2, y, t, z, a, part, pack, ode3_b, stream);
    }

    // ---- head: GAP + linear ----
    {
        int H = 24, HW = H * H, C = 256;
        stats_kernel<<<8 * C, 256, 0, stream>>>(y, mu, rs, HW, 1.f / HW);
        head_kernel<<<1, 128, 0, stream>>>(mu, head_w, head_b, out, C);
    }
}

// Round 17
// 5282.717 us; speedup vs baseline: 1.1861x; 1.1861x over previous
//
#include <hip/hip_runtime.h>

// ---------------------------------------------------------------------------
// MPNODE_STL10 forward, round 26: REVERT to r23 (verified best, 5289.6us).
//  - r25 (bf16-z) regressed: staging became scalar u16 loads -> the guide's
//    Common-mistake #2 (scalar bf16 loads ~2-2.5x slower); staging is the
//    latency critical path, so conv2 dispatches went 71 -> 94us despite
//    halved bytes and 2/3 the MFMAs. Lesson: these dispatches are bound by
//    load-issue latency structure, not work volume.
//  - r24 (depth-2 prefetch) also regressed: depth-1 is optimal here.
//  - This file is r23 verbatim: r16 structure + staging-geometry hoist
//    (goff[] per-item register array, icc-invariant; epilogue base hoist).
//  - Session ledger: 7032 -> 5289.6us (-25%) via WG-fattening (r10), ILP
//    conv1x1 + partials-stats + fused norm-pool (r12), shape hybrid (r16),
//    VALU hoist (r23). Persistent-stage arc (r18-r21) terminated: needs
//    per-round kernel-resource introspection to land safely.
// ---------------------------------------------------------------------------

typedef __attribute__((ext_vector_type(8)))  short  s16x8;
typedef __attribute__((ext_vector_type(16))) float  f32x16;

__device__ __forceinline__ unsigned short bf16_rtne(float f) {
    unsigned u = __builtin_bit_cast(unsigned, f);
    unsigned r = u + 0x7FFFu + ((u >> 16) & 1u);
    return (unsigned short)(r >> 16);
}
__device__ __forceinline__ void split2(float v, unsigned& h, unsigned& l) {
    unsigned u = __builtin_bit_cast(unsigned, v);
    h = (u + 0x7fffu + ((u >> 16) & 1u)) >> 16;
    float r = v - __builtin_bit_cast(float, h << 16);
    unsigned ur = __builtin_bit_cast(unsigned, r);
    l = (ur + 0x7fffu + ((ur >> 16) & 1u)) >> 16;
}
__device__ __forceinline__ unsigned packsplit(float v) {
    unsigned h, l; split2(v, h, l); return h | (l << 16);
}

// ---------------- weight pack (verified rounds 4-25) -----------------------
// Per dir (0=conv, 1=transposed+flipped), per bank(4):
//   [icc(C/16)][mt(C/32)][kp(9)][pl(2: hi,lo)][lane(64)][j(8)]
__global__ __launch_bounds__(256) void pack_weights(
    const float* __restrict__ Wb, unsigned short* __restrict__ out, int C)
{
    const int dir = blockIdx.y;
    const int MT = C >> 5, ICC = C >> 4;
    const size_t TOT = (size_t)36 * C * C;
    size_t t = (size_t)blockIdx.x * 256 + threadIdx.x;
    if (t >= TOT) return;
    int j = t & 7;
    int l = (t >> 3) & 63;
    size_t r = t >> 9;
    int kp  = r % 9;  r /= 9;
    int mt  = r % MT; r /= MT;
    int icc = r % ICC; r /= ICC;
    int bank = (int)r;
    int oc = mt * 32 + (l & 31);
    int ic = icc * 16 + (l >> 5) * 8 + j;
    int kh = kp / 3, kw = kp % 3;
    float v;
    if (dir == 0)
        v = Wb[(((size_t)(bank * C + oc) * C + ic) * 3 + kh) * 3 + kw];
    else
        v = Wb[(((size_t)(bank * C + ic) * C + oc) * 3 + (2 - kh)) * 3 + (2 - kw)];
    unsigned short h = bf16_rtne(v);
    float hf = __builtin_bit_cast(float, (unsigned)h << 16);
    unsigned short lo = bf16_rtne(v - hf);
    size_t idx = ((((size_t)bank * ICC + icc) * MT + mt) * 9 + kp) * 1024 + l * 8 + j;
    unsigned short* base = out + (size_t)dir * 72 * C * C;
    base[idx] = h;
    base[idx + 512] = lo;
}

// ---------------- MFMA conv kernel -----------------------------------------
// MODE 0: conv1, fp32 input (k1 stages from y)
// MODE 1: conv1, split-u32 input (k2-k4 stage from t; raw copy)
// MODE 2: conv2, split-u32 input (z) + instnorm; RK4 epilogue
// Stats: conv1 stores per-WG partials part[(n*MT+mt)*tilesT+tile][64]
//        ([0..31]=sum per oc, [32..63]=sumsq); conv2 reduces over tilesT.
template<int NW, int MODE>
__global__ __launch_bounds__(NW * 64) void conv_mfma4(
    const void* __restrict__ in,
    const unsigned short* __restrict__ pA,
    const float* __restrict__ bias,
    const float* __restrict__ partI,         // conv2: read partials
    float* __restrict__ partO,               // conv1: write partials
    const float* __restrict__ ybase, float* __restrict__ accb,
    float* __restrict__ ydstF, unsigned* __restrict__ ydstS,
    int C, int H, int W, int tilesX, int tilesT, float inv_hw,
    int mode, float acoef, float dt6)
{
    constexpr bool CONV2 = (MODE == 2);
    constexpr int TPX = 16, TPY = 2 * NW;
    constexpr int HX = TPX + 2, HY = TPY + 2;
    constexpr int NROW = HX * HY;
    constexpr int RS = 20;               // row stride (shorts), 40B
    constexpr int PL = NROW * RS;
    constexpr int BUFS = 2 * PL;         // hi plane + lo plane
    constexpr int NTHR = NW * 64;
    constexpr int NELEM = NROW * 16;
    constexpr int NIT = (NELEM + NTHR - 1) / NTHR;
    __shared__ __align__(16) unsigned short sB[2 * BUFS];
    __shared__ float sTab[CONV2 ? 512 : 4];

    const int tid = threadIdx.x;
    const int w = tid >> 6, lane = tid & 63;
    const int n = blockIdx.x;            // fastest dim -> image n on XCD n
    const int tile = blockIdx.y;
    const int mt = blockIdx.z;
    const int tileX = tile % tilesX, tileY = tile / tilesX;
    const int px0 = tileX * TPX, py0 = tileY * TPY;
    const int ocb = mt * 32;
    const int HW = H * W;
    const int ICC = C >> 4, MT = C >> 5;
    const int col = lane & 31, half = lane >> 5;
    const int xl = col & 15, yr = col >> 4;
    const int wy0 = 2 * w;
    const int ncbase = n * C;

    // ---- per-item staging geometry, invariant across icc chunks ----
    int goff[NIT];
#pragma unroll
    for (int i = 0; i < NIT; i++) {
        int e = tid + i * NTHR;
        int o = (int)0x80000000;
        if (e < NELEM) {
            int ic = e / NROW; int r = e - ic * NROW;
            int yy = r / HX, xx = r - yy * HX;
            int gy = py0 + yy - 1, gx = px0 + xx - 1;
            if (gy >= 0 && gy < H && gx >= 0 && gx < W)
                o = (ncbase + ic) * HW + gy * W + gx;
        }
        goff[i] = o;
    }

    float stg[NIT];
    // raw loads only: MODE 0 fp32, MODE 1/2 split-u32 bit pattern
    auto stageLoad = [&](int icc) {
        const int cofs = icc * 16 * HW;
#pragma unroll
        for (int i = 0; i < NIT; i++) {
            float v = 0.f;
            int o = goff[i];
            if (o >= 0) {
                if (MODE == 0)
                    v = ((const float*)in)[o + cofs];
                else
                    v = __builtin_bit_cast(float, ((const unsigned*)in)[o + cofs]);
            }
            stg[i] = v;
        }
    };
    // MODE 2 normalizes here (needs sTab, available after the stats barrier)
    auto stageWrite = [&](int b, int c0) {
#pragma unroll
        for (int i = 0; i < NIT; i++) {
            int e = tid + i * NTHR;
            if (e < NELEM) {
                int ic = e / NROW; int r = e - ic * NROW;
                unsigned h, l;
                if (MODE == 1) {
                    unsigned u = __builtin_bit_cast(unsigned, stg[i]);
                    h = u & 0xffffu; l = u >> 16;
                } else if (MODE == 2) {
                    float v = 0.f;
                    if (goff[i] >= 0) {
                        unsigned u = __builtin_bit_cast(unsigned, stg[i]);
                        float vh = __builtin_bit_cast(float, u << 16);
                        float vl = __builtin_bit_cast(float, u & 0xffff0000u);
                        int c = c0 + ic;
                        v = (vh + vl - sTab[2 * c]) * sTab[2 * c + 1];
                    }
                    split2(v, h, l);
                } else {
                    split2(stg[i], h, l);
                }
                int off = b * BUFS + r * RS + ic;
                sB[off] = (unsigned short)h;
                sB[off + PL] = (unsigned short)l;
            }
        }
    };
    auto loadB = [&](int b, int kp, s16x8& oh, s16x8& ol) {
        int kh = kp / 3, kw = kp - kh * 3;
        int px = (wy0 + yr + kh) * HX + (xl + kw);
        int off = b * BUFS + px * RS + half * 8;
        oh = *(const s16x8*)&sB[off];
        ol = *(const s16x8*)&sB[off + PL];
    };

    f32x16 accA{}, accB{}, accC{};

    // issue chunk-0 loads first: latency hides under the stats reduce
    stageLoad(0);

    // conv2: per-channel mu/rstd from conv1's per-tile partials.
    // Parallel over all NTHR threads: (slice, channel) partials -> LDS tree.
    if (CONV2) {
        float* sRed = (float*)sB;        // scratch; free until stageWrite(0)
        const int g = NTHR / C;          // slices per channel (>=1)
        {
            int c0 = tid % C, sl = tid / C;
            int mtc = c0 >> 5, occ = c0 & 31;
            int t0 = (tilesT * sl) / g, t1 = (tilesT * (sl + 1)) / g;
            const float* pb = partI + ((size_t)(n * MT + mtc) * tilesT) * 64 + occ;
            float S = 0.f, Q = 0.f;
            for (int tt = t0; tt < t1; ++tt) {
                S += pb[(size_t)tt * 64];
                Q += pb[(size_t)tt * 64 + 32];
            }
            sRed[tid] = S;
            sRed[NTHR + tid] = Q;
        }
        __syncthreads();
        if (tid < C) {
            float s = 0.f, q = 0.f;
            for (int k = 0; k < g; ++k) {
                s += sRed[k * C + tid];
                q += sRed[NTHR + k * C + tid];
            }
            float m = s * inv_hw;
            sTab[2 * tid] = m;
            sTab[2 * tid + 1] = rsqrtf(fmaf(-m, m, q * inv_hw) + 1e-5f);
        }
        __syncthreads();
    }

    stageWrite(0, 0);
    __syncthreads();

    for (int icc = 0; icc < ICC; ++icc) {
        // ---- bulk A loads: whole chunk's 9 kp hi+lo into regs ----
        s16x8 aH[9], aL[9];
        {
            const unsigned short* ab =
                pA + ((size_t)(icc * MT + mt)) * 9216 + lane * 8;
#pragma unroll
            for (int kp = 0; kp < 9; ++kp) {
                aH[kp] = *(const s16x8*)(ab + kp * 1024);
                aL[kp] = *(const s16x8*)(ab + kp * 1024 + 512);
            }
        }
        const int b = icc & 1;
        if (icc + 1 < ICC) stageLoad(icc + 1);   // stays outstanding over MFMAs

        s16x8 bh, bl;
        loadB(b, 0, bh, bl);
#pragma unroll
        for (int kp = 0; kp < 9; ++kp) {
            s16x8 bhn, bln;
            if (kp < 8) loadB(b, kp + 1, bhn, bln);
            accA = __builtin_amdgcn_mfma_f32_32x32x16_bf16(aH[kp], bh, accA, 0, 0, 0);
            accB = __builtin_amdgcn_mfma_f32_32x32x16_bf16(aL[kp], bh, accB, 0, 0, 0);
            accC = __builtin_amdgcn_mfma_f32_32x32x16_bf16(aH[kp], bl, accC, 0, 0, 0);
            if (kp < 8) { bh = bhn; bl = bln; }
        }
        if (icc + 1 < ICC) {
            stageWrite(b ^ 1, (icc + 1) * 16);
            __syncthreads();
        }
    }

    // ---- epilogue: C/D layout col=lane&31, row=(r&3)+8*(r>>2)+4*half ----
    const int gx = px0 + xl;
    const int gy = py0 + wy0 + yr;
    const bool valid = (gx < W);
    const size_t base0 = (size_t)(ncbase + ocb) * HW + (size_t)gy * W + gx;
    float* sred = (float*)sB;   // last chunk used buffer 1 (ICC even); buf 0 free
#pragma unroll
    for (int r = 0; r < 16; r++) {
        int row = (r & 3) + 8 * (r >> 2) + 4 * half;
        int oc = ocb + row;
        size_t idx = base0 + (size_t)(row * HW);
        float v = accA[r] + accB[r] + accC[r];
        if (!CONV2) {
            v += bias[oc];
            v = fmaxf(v, 0.f);
            if (valid) ydstS[idx] = packsplit(v);      // z, split-u32
            float s = valid ? v : 0.f;
            float sq = s * s;
#pragma unroll
            for (int m = 1; m < 32; m <<= 1) {
                s  += __shfl_xor(s, m, 64);
                sq += __shfl_xor(sq, m, 64);
            }
            if ((lane & 31) == 0) {
                int slot = ((w * 2 + half) * 16 + r) * 2;
                sred[slot] = s;
                sred[slot + 1] = sq;
            }
        } else if (valid) {
            float k = -v;
            if (mode == 0) {
                accb[idx] = k;
                ydstS[idx] = packsplit(ybase[idx] + acoef * k);   // t
            } else if (mode == 3) {
                ydstF[idx] = ybase[idx] + dt6 * (accb[idx] + k);  // y, fp32
            } else {
                accb[idx] += 2.f * k;
                ydstS[idx] = packsplit(ybase[idx] + acoef * k);   // t
            }
        }
    }
    if (!CONV2) {
        __syncthreads();
        if (tid < 32) {
            // row==tid mapping (verified): tid bits = (r&3)|h2<<2|(r>>2)<<3
            int h2 = (tid >> 2) & 1;
            int r  = (tid & 3) | ((tid >> 3) << 2);
            float s = 0.f, sq = 0.f;
#pragma unroll
            for (int wv = 0; wv < NW; wv++) {
                int slot = ((wv * 2 + h2) * 16 + r) * 2;
                s  += sred[slot];
                sq += sred[slot + 1];
            }
            float* po = partO + ((size_t)(n * MT + mt) * tilesT + tile) * 64;
            po[tid] = s;
            po[tid + 32] = sq;
        }
    }
}

// ---------------- fp32 stem conv (Cin=3, Cout=64, 2 px/thread) -------------
__global__ __launch_bounds__(256) void conv3x3_stem(
    const float* __restrict__ in, const float* __restrict__ w,
    const float* __restrict__ bias, float* __restrict__ out,
    int H, int W, int tilesX)
{
    __shared__ float sIn[3][18][34];
    __shared__ float sW[16][3][9];
    const int tid = threadIdx.x;
    const int tx = tid & 15, ty = tid >> 4;
    const int tileX = blockIdx.x % tilesX, tileY = blockIdx.x / tilesX;
    const int x0 = tileX * 32, y0 = tileY * 16;
    const int oc0 = blockIdx.y * 16;
    const int n = blockIdx.z;
    const int HW = H * W;

    for (int idx = tid; idx < 3 * 18 * 34; idx += 256) {
        int c = idx / (18 * 34); int r = idx % (18 * 34);
        int iy = r / 34, ix = r % 34;
        int gy = y0 + iy - 1, gx = x0 + ix - 1;
        float v = 0.f;
        if (gy >= 0 && gy < H && gx >= 0 && gx < W)
            v = in[(size_t)(n * 3 + c) * HW + gy * W + gx];
        sIn[c][iy][ix] = v;
    }
    for (int idx = tid; idx < 16 * 27; idx += 256) {
        int o = idx / 27, r = idx % 27;
        sW[o][r / 9][r % 9] = w[(size_t)(oc0 + o) * 27 + r];
    }
    __syncthreads();

    float a0[16], a1[16];
#pragma unroll
    for (int o = 0; o < 16; o++) { a0[o] = 0.f; a1[o] = 0.f; }
#pragma unroll
    for (int c = 0; c < 3; c++)
#pragma unroll
        for (int kh = 0; kh < 3; kh++)
#pragma unroll
            for (int kw = 0; kw < 3; kw++) {
                float v0 = sIn[c][ty + kh][tx + kw];
                float v1 = sIn[c][ty + kh][tx + 16 + kw];
#pragma unroll
                for (int o = 0; o < 16; o++) {
                    float wv = sW[o][c][kh * 3 + kw];
                    a0[o] = fmaf(v0, wv, a0[o]);
                    a1[o] = fmaf(v1, wv, a1[o]);
                }
            }

    const int gy = y0 + ty, gx = x0 + tx;
#pragma unroll
    for (int o = 0; o < 16; o++) {
        float bb = bias[oc0 + o];
        size_t base = (size_t)(n * 64 + oc0 + o) * HW + (size_t)gy * W + gx;
        out[base] = a0[o] + bb;
        out[base + 16] = a1[o] + bb;
    }
}

// ---------------- instance-norm stats (stem/conn/head only) ----------------
__global__ __launch_bounds__(256) void stats_kernel(
    const float* __restrict__ x, float* __restrict__ mu, float* __restrict__ rstd,
    int HW, float inv_hw)
{
    int nc = blockIdx.x;
    const float* p = x + (size_t)nc * HW;
    float s = 0.f, ss = 0.f;
    for (int i = threadIdx.x; i < HW; i += 256) {
        float v = p[i];
        s += v;
        ss = fmaf(v, v, ss);
    }
    for (int off = 32; off; off >>= 1) {
        s  += __shfl_down(s, off, 64);
        ss += __shfl_down(ss, off, 64);
    }
    __shared__ float aS[4], aSS[4];
    int wid = threadIdx.x >> 6, lane = threadIdx.x & 63;
    if (lane == 0) { aS[wid] = s; aSS[wid] = ss; }
    __syncthreads();
    if (threadIdx.x == 0) {
        s  = aS[0] + aS[1] + aS[2] + aS[3];
        ss = aSS[0] + aSS[1] + aSS[2] + aSS[3];
        float m = s * inv_hw;
        float var = fmaf(-m, m, ss * inv_hw);
        mu[nc] = m;
        rstd[nc] = rsqrtf(var + 1e-5f);
    }
}

__global__ __launch_bounds__(256) void norm_affine_relu_kernel(
    const float* __restrict__ in, float* __restrict__ out,
    const float* __restrict__ mu, const float* __restrict__ rstd,
    const float* __restrict__ g, const float* __restrict__ b,
    int C, int HW, size_t total)
{
    size_t i = (size_t)blockIdx.x * 256 + threadIdx.x;
    if (i >= total) return;
    size_t nc = i / HW;
    int c = (int)(nc % C);
    float v = (in[i] - mu[nc]) * rstd[nc] * g[c] + b[c];
    out[i] = fmaxf(v, 0.f);
}

// ---------------- fused norm+relu+avgpool2 (conn blocks) -------------------
__global__ __launch_bounds__(256) void norm_pool_kernel(
    const float* __restrict__ in, float* __restrict__ out,
    const float* __restrict__ mu, const float* __restrict__ rstd,
    const float* __restrict__ g, const float* __restrict__ b,
    int C, int Ho, int Wo, size_t total)
{
    size_t i = (size_t)blockIdx.x * 256 + threadIdx.x;
    if (i >= total) return;
    int wo = (int)(i % Wo);
    int ho = (int)((i / Wo) % Ho);
    size_t nc = i / ((size_t)Wo * Ho);
    int c = (int)(nc % C);
    const int Wi = 2 * Wo;
    const float* p = in + nc * (size_t)(4 * Ho * Wo) + (size_t)(2 * ho) * Wi + 2 * wo;
    float sc  = rstd[nc] * g[c];
    float off = fmaf(-mu[nc], sc, b[c]);
    float2 t0 = *(const float2*)p;
    float2 t1 = *(const float2*)(p + Wi);
    float s = fmaxf(fmaf(t0.x, sc, off), 0.f) + fmaxf(fmaf(t0.y, sc, off), 0.f)
            + fmaxf(fmaf(t1.x, sc, off), 0.f) + fmaxf(fmaf(t1.y, sc, off), 0.f);
    out[i] = 0.25f * s;
}

// ---------------- 1x1 conv: 4 px/thread via float4, ILP ic loop ------------
#define C1OCT 8
__global__ __launch_bounds__(256) void conv1x1_kernel(
    const float* __restrict__ in, const float* __restrict__ w,
    const float* __restrict__ bias, float* __restrict__ out,
    int Cin, int Cout, int HW)
{
    const int HW4 = HW >> 2;
    int p = blockIdx.x * 256 + threadIdx.x;
    if (p >= HW4) return;
    const int oc0 = blockIdx.y * C1OCT;
    const int n = blockIdx.z;
    const float4* ip = (const float4*)(in + (size_t)n * Cin * HW) + p;
    float acc[C1OCT][4];
#pragma unroll
    for (int o = 0; o < C1OCT; o++)
        acc[o][0] = acc[o][1] = acc[o][2] = acc[o][3] = 0.f;
#pragma unroll 4
    for (int ic = 0; ic < Cin; ic++) {
        float4 v = ip[(size_t)ic * HW4];
#pragma unroll
        for (int o = 0; o < C1OCT; o++) {
            float wv = w[(size_t)(oc0 + o) * Cin + ic];
            acc[o][0] = fmaf(v.x, wv, acc[o][0]);
            acc[o][1] = fmaf(v.y, wv, acc[o][1]);
            acc[o][2] = fmaf(v.z, wv, acc[o][2]);
            acc[o][3] = fmaf(v.w, wv, acc[o][3]);
        }
    }
    float4* op = (float4*)(out + ((size_t)n * Cout + oc0) * HW) + p;
#pragma unroll
    for (int o = 0; o < C1OCT; o++) {
        float bb = bias[oc0 + o];
        float4 r;
        r.x = acc[o][0] + bb; r.y = acc[o][1] + bb;
        r.z = acc[o][2] + bb; r.w = acc[o][3] + bb;
        op[(size_t)o * HW4] = r;
    }
}

__global__ __launch_bounds__(128) void head_kernel(
    const float* __restrict__ m, const float* __restrict__ hw,
    const float* __restrict__ hb, float* __restrict__ out, int C)
{
    int t = threadIdx.x;
    if (t < 80) {
        int n = t / 10, k = t % 10;
        float acc = hb[k];
        for (int c = 0; c < C; c++)
            acc = fmaf(m[n * C + c], hw[k * C + c], acc);
        out[t] = acc;
    }
}

// ---------------------------------------------------------------------------
// host orchestration
// ---------------------------------------------------------------------------
struct OdeCfg { int C, H, tilesX, tilesT; };
// stage0: NW=8 -> tile 16x16: 6x6 = 36 tiles
// stage1: NW=4 -> tile 16x8:  3x6 = 18 tiles
// stage2: NW=4 -> tile 16x8:  2x3 = 6 tiles (x-masked)
static const OdeCfg CFG[3] = {
    {64, 96, 6, 36},
    {128, 48, 3, 18},
    {256, 24, 2, 6},
};

static void launch_c1(int st, int inMode, const void* in, const unsigned short* pA,
                      const float* bias, float* part, unsigned* z, hipStream_t s)
{
    const OdeCfg& c = CFG[st];
    dim3 g(8, c.tilesT, c.C / 32);   // n fastest -> image n on XCD n
    float ih = 1.f / (c.H * c.H);
    if (st == 0) {
        if (inMode == 0)
            conv_mfma4<8, 0><<<g, 512, 0, s>>>(in, pA, bias,
                nullptr, part, nullptr, nullptr, nullptr, z,
                c.C, c.H, c.H, c.tilesX, c.tilesT, ih, 0, 0.f, 0.f);
        else
            conv_mfma4<8, 1><<<g, 512, 0, s>>>(in, pA, bias,
                nullptr, part, nullptr, nullptr, nullptr, z,
                c.C, c.H, c.H, c.tilesX, c.tilesT, ih, 0, 0.f, 0.f);
    } else {
        if (inMode == 0)
            conv_mfma4<4, 0><<<g, 256, 0, s>>>(in, pA, bias,
                nullptr, part, nullptr, nullptr, nullptr, z,
                c.C, c.H, c.H, c.tilesX, c.tilesT, ih, 0, 0.f, 0.f);
        else
            conv_mfma4<4, 1><<<g, 256, 0, s>>>(in, pA, bias,
                nullptr, part, nullptr, nullptr, nullptr, z,
                c.C, c.H, c.H, c.tilesX, c.tilesT, ih, 0, 0.f, 0.f);
    }
}

static void launch_c2(int st, const unsigned* z, const unsigned short* pA,
                      const float* part,
                      const float* ybase, float* accb,
                      float* ydstF, unsigned* ydstS,
                      int mode, float acoef, hipStream_t s)
{
    const OdeCfg& c = CFG[st];
    dim3 g(8, c.tilesT, c.C / 32);
    float ih = 1.f / (c.H * c.H);
    const float dt6 = 0.25f / 6.f;
    if (st == 0)
        conv_mfma4<8, 2><<<g, 512, 0, s>>>(z, pA, nullptr,
            part, nullptr, ybase, accb, ydstF, ydstS,
            c.C, c.H, c.H, c.tilesX, c.tilesT, ih, mode, acoef, dt6);
    else
        conv_mfma4<4, 2><<<g, 256, 0, s>>>(z, pA, nullptr,
            part, nullptr, ybase, accb, ydstF, ydstS,
            c.C, c.H, c.H, c.tilesX, c.tilesT, ih, mode, acoef, dt6);
}

static void ode_block_mfma(int st, float* y, unsigned* t, unsigned* z, float* a,
                           float* part, unsigned short* pack,
                           const float* bbank, hipStream_t s)
{
    const OdeCfg& c = CFG[st];
    const int C = c.C;
    const size_t BANKW = (size_t)18 * C * C;   // one bank, one dir
    const size_t DIRW  = (size_t)72 * C * C;   // 4 banks
    const float dt = 0.25f;
    for (int i = 0; i < 4; i++) {
        int j = (i + 1 > 3) ? 3 : i + 1;
        const unsigned short* p1  = pack + i * BANKW;         // dir0, bank i
        const unsigned short* p1t = pack + DIRW + i * BANKW;  // dir1, bank i
        const unsigned short* p4  = pack + j * BANKW;
        const unsigned short* p4t = pack + DIRW + j * BANKW;
        const float* b1 = bbank + (size_t)i * C;
        const float* b4 = bbank + (size_t)j * C;

        // k1 (from fp32 y)
        launch_c1(st, 0, y, p1, b1, part, z, s);
        launch_c2(st, z, p1t, part, y, a, nullptr, t, 0, 0.5f * dt, s);
        // k2 (from split t)
        launch_c1(st, 1, t, p1, b1, part, z, s);
        launch_c2(st, z, p1t, part, y, a, nullptr, t, 1, 0.5f * dt, s);
        // k3
        launch_c1(st, 1, t, p1, b1, part, z, s);
        launch_c2(st, z, p1t, part, y, a, nullptr, t, 1, dt, s);
        // k4 + update (y out, fp32)
        launch_c1(st, 1, t, p4, b4, part, z, s);
        launch_c2(st, z, p4t, part, y, a, y, t, 3, 0.f, s);
    }
}

extern "C" void kernel_launch(void* const* d_in, const int* in_sizes, int n_in,
                              void* d_out, int out_size, void* d_ws, size_t ws_size,
                              hipStream_t stream)
{
    const float* x       = (const float*)d_in[0];
    const float* stem_w  = (const float*)d_in[1];
    const float* stem_b  = (const float*)d_in[2];
    const float* norm1_g = (const float*)d_in[3];
    const float* norm1_b = (const float*)d_in[4];
    const float* ode1_W  = (const float*)d_in[5];
    const float* ode1_b  = (const float*)d_in[6];
    const float* conn1_w = (const float*)d_in[7];
    const float* conn1_b = (const float*)d_in[8];
    const float* norm3_g = (const float*)d_in[9];
    const float* norm3_b = (const float*)d_in[10];
    const float* ode2_W  = (const float*)d_in[11];
    const float* ode2_b  = (const float*)d_in[12];
    const float* conn2_w = (const float*)d_in[13];
    const float* conn2_b = (const float*)d_in[14];
    const float* norm4_g = (const float*)d_in[15];
    const float* norm4_b = (const float*)d_in[16];
    const float* ode3_W  = (const float*)d_in[17];
    const float* ode3_b  = (const float*)d_in[18];
    const float* head_w  = (const float*)d_in[19];
    const float* head_b  = (const float*)d_in[20];
    float* out = (float*)d_out;

    float* ws = (float*)d_ws;
    const size_t BUF = 4718592; // 8*64*96*96 elements
    float*    y  = ws;
    unsigned* t  = (unsigned*)(ws + BUF);     // split-bf16 state t / conn scratch
    unsigned* z  = (unsigned*)(ws + 2 * BUF); // split-bf16 activations z
    float*    a  = ws + 3 * BUF;              // fp32 RK4 accumulator
    float*    mu = ws + 4 * BUF;              // 2048
    float*    rs = mu + 2048;                 // 2048
    float*    part = ws + 4 * BUF + 4096;     // per-WG stats partials (36864)
    unsigned short* pack = (unsigned short*)(ws + 4 * BUF + 4096 + 36864);
    float* tf = (float*)t;                    // conn scratch reuse (fp32)

    // ---- stem: conv3x3(3->64)+b -> IN(affine) -> relu ----
    {
        int H = 96;
        dim3 grid(3 * 6, 4, 8);              // 32x16 tiles, 16-oc blocks
        conv3x3_stem<<<grid, 256, 0, stream>>>(x, stem_w, stem_b, (float*)z,
                                               H, H, 3);
        stats_kernel<<<8 * 64, 256, 0, stream>>>((float*)z, mu, rs, H * H, 1.f / (H * H));
        size_t total = (size_t)8 * 64 * H * H;
        norm_affine_relu_kernel<<<(total + 255) / 256, 256, 0, stream>>>(
            (float*)z, y, mu, rs, norm1_g, norm1_b, 64, H * H, total);
    }

    // ---- ode1 ----
    {
        size_t TOT = (size_t)36 * 64 * 64;
        pack_weights<<<dim3((TOT + 255) / 256, 2), 256, 0, stream>>>(ode1_W, pack, 64);
        ode_block_mfma(0, y, t, z, a, part, pack, ode1_b, stream);
    }

    // ---- conn1: 1x1(64->128) -> IN+relu -> pool (fused) ----
    {
        int H = 96, HW = H * H, Cin = 64, Cout = 128;
        dim3 grid((HW / 4 + 255) / 256, Cout / C1OCT, 8);
        conv1x1_kernel<<<grid, 256, 0, stream>>>(y, conn1_w, conn1_b, tf, Cin, Cout, HW);
        stats_kernel<<<8 * Cout, 256, 0, stream>>>(tf, mu, rs, HW, 1.f / HW);
        size_t ptotal = (size_t)8 * Cout * 48 * 48;
        norm_pool_kernel<<<(ptotal + 255) / 256, 256, 0, stream>>>(
            tf, y, mu, rs, norm3_g, norm3_b, Cout, 48, 48, ptotal);
    }

    // ---- ode2 ----
    {
        size_t TOT = (size_t)36 * 128 * 128;
        pack_weights<<<dim3((TOT + 255) / 256, 2), 256, 0, stream>>>(ode2_W, pack, 128);
        ode_block_mfma(1, y, t, z, a, part, pack, ode2_b, stream);
    }

    // ---- conn2: 1x1(128->256) -> IN+relu -> pool (fused) ----
    {
        int H = 48, HW = H * H, Cin = 128, Cout = 256;
        dim3 grid((HW / 4 + 255) / 256, Cout / C1OCT, 8);
        conv1x1_kernel<<<grid, 256, 0, stream>>>(y, conn2_w, conn2_b, tf, Cin, Cout, HW);
        stats_kernel<<<8 * Cout, 256, 0, stream>>>(tf, mu, rs, HW, 1.f / HW);
        size_t ptotal = (size_t)8 * Cout * 24 * 24;
        norm_pool_kernel<<<(ptotal + 255) / 256, 256, 0, stream>>>(
            tf, y, mu, rs, norm4_g, norm4_b, Cout, 24, 24, ptotal);
    }

    // ---- ode3 ----
    {
        size_t TOT = (size_t)36 * 256 * 256;
        pack_weights<<<dim3((TOT + 255) / 256, 2), 256, 0, stream>>>(ode3_W, pack, 256);
        ode_block_mfma(2, y, t, z, a, part, pack, ode3_b, stream);
    }

    // ---- head: GAP + linear ----
    {
        int H = 24, HW = H * H, C = 256;
        stats_kernel<<<8 * C, 256, 0, stream>>>(y, mu, rs, HW, 1.f / HW);
        head_kernel<<<1, 128, 0, stream>>>(mu, head_w, head_b, out, C);
    }
}